// Round 10
// baseline (205.246 us; speedup 1.0000x reference)
//
#include <hip/hip_runtime.h>

#define FDIM 128
#define NGRP 8

typedef __attribute__((ext_vector_type(4))) float f32x4;
typedef __attribute__((ext_vector_type(8))) short s16x8;
typedef __attribute__((ext_vector_type(4))) short s16x4;

__device__ inline unsigned short f2bf(float f) {      // RNE f32->bf16
    unsigned u = __builtin_bit_cast(unsigned, f);
    u += 0x7FFFu + ((u >> 16) & 1u);
    return (unsigned short)(u >> 16);
}
__device__ inline float bflo(unsigned u) { return __builtin_bit_cast(float, u << 16); }
__device__ inline float bfhi(unsigned u) { return __builtin_bit_cast(float, u & 0xFFFF0000u); }

// =============== zero degg + lookback-state (runtime fill is latency-bound) ===============
__global__ void zero_kernel(int4* __restrict__ p, int n4) {
    int i = blockIdx.x * blockDim.x + threadIdx.x;
    if (i < n4) p[i] = make_int4(0, 0, 0, 0);
}

// =============== hist8 + weight transpose riding as extra blocks ===============
__global__ void hist8w_kernel(const int* __restrict__ dst, int* __restrict__ degg, int E, int N, int EB,
                              const float* __restrict__ Wl0, const float* __restrict__ Wr0,
                              const float* __restrict__ Wl1, const float* __restrict__ Wr1,
                              short* __restrict__ Wt0, short* __restrict__ Wt1) {
    int bid = blockIdx.x;
    if (bid < EB) {
        int e = bid * 256 + threadIdx.x;
        if (e < E) atomicAdd(&degg[(bid & 7) * N + dst[e]], 1);
    } else {
        int g = (bid - EB) * 256 + threadIdx.x;   // [0, 65536)
        int n = g & 127;
        int k = (g >> 7) & 255;
        int layer = g >> 15;
        const float* Wl = layer ? Wl1 : Wl0;
        const float* Wr = layer ? Wr1 : Wr0;
        short* Wt = layer ? Wt1 : Wt0;
        float v = (k < 128) ? Wl[k * 128 + n] : Wr[(k - 128) * 128 + n];
        Wt[n * 256 + k] = (short)f2bf(v);
    }
}

// =============== single-pass exclusive scan, decoupled lookback ===============
// state[bid] single-word descriptor: flag(2b)<<30 | value(30b). flag: 0 invalid,
// 1 aggregate, 2 inclusive-prefix. Values <= E=800000 fit in 30 bits.
// All 391 blocks co-resident (256 threads, 1KB LDS) -> lookback can't deadlock.
__global__ __launch_bounds__(256)
void scan_kernel(const int* __restrict__ in, int* __restrict__ out, int* __restrict__ cursor,
                 unsigned* __restrict__ state, int M, int E) {
    __shared__ int s[256];
    __shared__ int s_excl;
    const int bid = blockIdx.x;
    const int t = threadIdx.x;
    int base = bid * 1024 + t * 4;
    int4 v = make_int4(0, 0, 0, 0);
    if (base + 3 < M) v = *reinterpret_cast<const int4*>(in + base);
    else {
        if (base + 0 < M) v.x = in[base + 0];
        if (base + 1 < M) v.y = in[base + 1];
        if (base + 2 < M) v.z = in[base + 2];
    }
    int tsum = v.x + v.y + v.z + v.w;
    s[t] = tsum;
    __syncthreads();
    for (int o2 = 1; o2 < 256; o2 <<= 1) {
        int tt = (t >= o2) ? s[t - o2] : 0;
        __syncthreads();
        s[t] += tt;
        __syncthreads();
    }
    int total = s[255];
    int texcl = s[t] - tsum;

    if (t == 0) {   // publish aggregate (block 0 publishes final prefix directly)
        unsigned w = ((bid == 0 ? 2u : 1u) << 30) | (unsigned)total;
        __hip_atomic_store(&state[bid], w, __ATOMIC_RELEASE, __HIP_MEMORY_SCOPE_AGENT);
    }
    if (t < 64) {   // wave-0 cooperative lookback, windows of 64 predecessors
        int excl = 0;
        int j = bid - 1;
        while (j >= 0) {
            int idx = j - t;   // lane 0 = closest predecessor
            unsigned w = 0;
            if (idx >= 0) {
                do {
                    w = __hip_atomic_load(&state[idx], __ATOMIC_ACQUIRE, __HIP_MEMORY_SCOPE_AGENT);
                } while ((w >> 30) == 0u);
            }
            int val = (int)(w & 0x3FFFFFFFu);
            bool isPre = (idx >= 0) && ((w >> 30) == 2u);
            unsigned long long mask = __ballot(isPre);
            int contrib;
            if (mask) {
                int stop = __ffsll((unsigned long long)mask) - 1;  // closest PRE
                contrib = (t <= stop) ? val : 0;   // aggregates after it + its prefix
            } else {
                contrib = (idx >= 0) ? val : 0;
            }
            for (int o = 32; o > 0; o >>= 1) contrib += __shfl_down(contrib, o);
            excl += contrib;                        // lane 0 only is meaningful
            if (mask) break;
            j -= 64;
        }
        if (t == 0) {
            s_excl = excl;
            unsigned w = (2u << 30) | (unsigned)(excl + total);
            __hip_atomic_store(&state[bid], w, __ATOMIC_RELEASE, __HIP_MEMORY_SCOPE_AGENT);
        }
    }
    __syncthreads();
    int b = s_excl;

    int e0 = b + texcl;
    int4 o;
    o.x = e0; o.y = o.x + v.x; o.z = o.y + v.y; o.w = o.z + v.z;
    if (base + 3 < M) {
        *reinterpret_cast<int4*>(out + base) = o;
        *reinterpret_cast<int4*>(cursor + base) = o;
    } else {
#pragma unroll
        for (int j2 = 0; j2 < 3; ++j2) {
            int vv = (j2 == 0) ? o.x : (j2 == 1) ? o.y : o.z;
            if (base + j2 < M) { out[base + j2] = vv; cursor[base + j2] = vv; }
        }
    }
    if (bid == 0 && t == 0) out[M] = E;
}

// =============== fill8 + x->bf16 conversion riding as extra blocks ===============
__global__ void fill8x_kernel(const int* __restrict__ src, const int* __restrict__ dst,
                              int* __restrict__ cursor, int* __restrict__ eidt, int E, int N, int EB,
                              const float* __restrict__ x, short* __restrict__ xb, int n4x) {
    int bid = blockIdx.x;
    if (bid < EB) {
        int e = bid * 256 + threadIdx.x;
        if (e < E) {
            int p = atomicAdd(&cursor[(bid & 7) * N + dst[e]], 1);
            eidt[p] = src[e];
        }
    } else {
        int i = (bid - EB) * 256 + threadIdx.x;
        if (i < n4x) {
            float4 v = reinterpret_cast<const float4*>(x)[i];
            s16x4 o;
            o[0] = (short)f2bf(v.x); o[1] = (short)f2bf(v.y);
            o[2] = (short)f2bf(v.z); o[3] = (short)f2bf(v.w);
            reinterpret_cast<s16x4*>(xb)[i] = o;
        }
    }
}

// =============== merge 8 group-runs -> dense eid; computes+writes rp inline ===============
__global__ void merge_kernel(const int* __restrict__ off, const int* __restrict__ eidt,
                             int* __restrict__ rp, int* __restrict__ eid, int N, int E) {
    __shared__ int S0;
    if (threadIdx.x == 0) {
        int s = 0;
#pragma unroll
        for (int g = 0; g < NGRP; ++g) s += off[g * N];
        S0 = s;
    }
    __syncthreads();
    int i = blockIdx.x * 256 + threadIdx.x;
    if (i > N) return;
    if (i == N) { rp[N] = E; return; }
    int bs[NGRP], es[NGRP];
    int si = 0;
#pragma unroll
    for (int g = 0; g < NGRP; ++g) {
        bs[g] = off[g * N + i];
        es[g] = off[g * N + i + 1];   // g=7,i=N-1 -> off[M]=E, correct
        si += bs[g];
    }
    int dp = si - S0;
    rp[i] = dp;
#pragma unroll
    for (int g = 0; g < NGRP; ++g)
        for (int k = bs[g]; k < es[g]; ++k) eid[dp++] = eidt[k];
}

// ============ gather v3: 16 neighbor rows in flight per iteration (R9-proven) ============
#define ACC8(v) { a[0]+=bflo(v.x); a[1]+=bfhi(v.x); a[2]+=bflo(v.y); a[3]+=bfhi(v.y); \
                  a[4]+=bflo(v.z); a[5]+=bfhi(v.z); a[6]+=bflo(v.w); a[7]+=bfhi(v.w); }

__global__ void gather_kernel(const short* __restrict__ X, const int* __restrict__ rp,
                              const int* __restrict__ eid, short* __restrict__ mb, int N) {
    int node = blockIdx.x * (blockDim.x >> 6) + (threadIdx.x >> 6);
    int lane = threadIdx.x & 63;
    int g = lane >> 4;
    int c = lane & 15;
    if (node >= N) return;
    int beg = rp[node], end = rp[node + 1];
    float a[8];
#pragma unroll
    for (int j = 0; j < 8; ++j) a[j] = 0.0f;

    int k = beg;
    for (; k + 16 <= end; k += 16) {
        int s0 = eid[k + g];
        int s1 = eid[k + 4 + g];
        int s2 = eid[k + 8 + g];
        int s3 = eid[k + 12 + g];
        uint4 v0 = *reinterpret_cast<const uint4*>(X + (size_t)s0 * FDIM + c * 8);
        uint4 v1 = *reinterpret_cast<const uint4*>(X + (size_t)s1 * FDIM + c * 8);
        uint4 v2 = *reinterpret_cast<const uint4*>(X + (size_t)s2 * FDIM + c * 8);
        uint4 v3 = *reinterpret_cast<const uint4*>(X + (size_t)s3 * FDIM + c * 8);
        ACC8(v0); ACC8(v1); ACC8(v2); ACC8(v3);
    }
    if (k + 8 <= end) {
        int s0 = eid[k + g];
        int s1 = eid[k + 4 + g];
        uint4 v0 = *reinterpret_cast<const uint4*>(X + (size_t)s0 * FDIM + c * 8);
        uint4 v1 = *reinterpret_cast<const uint4*>(X + (size_t)s1 * FDIM + c * 8);
        ACC8(v0); ACC8(v1);
        k += 8;
    }
    if (k + 4 <= end) {
        int s0 = eid[k + g];
        uint4 v0 = *reinterpret_cast<const uint4*>(X + (size_t)s0 * FDIM + c * 8);
        ACC8(v0);
        k += 4;
    }
    int rem = end - k;                        // 0..3
    if (g < rem) {
        int s0 = eid[k + g];
        uint4 v0 = *reinterpret_cast<const uint4*>(X + (size_t)s0 * FDIM + c * 8);
        ACC8(v0);
    }

#pragma unroll
    for (int j = 0; j < 8; ++j) a[j] += __shfl_xor(a[j], 16);
#pragma unroll
    for (int j = 0; j < 8; ++j) a[j] += __shfl_xor(a[j], 32);

    if (g == 0) {
        float inv = (end > beg) ? 1.0f / (float)(end - beg) : 0.0f;
        uint4 o;
        o.x = (unsigned)f2bf(a[0] * inv) | ((unsigned)f2bf(a[1] * inv) << 16);
        o.y = (unsigned)f2bf(a[2] * inv) | ((unsigned)f2bf(a[3] * inv) << 16);
        o.z = (unsigned)f2bf(a[4] * inv) | ((unsigned)f2bf(a[5] * inv) << 16);
        o.w = (unsigned)f2bf(a[6] * inv) | ((unsigned)f2bf(a[7] * inv) << 16);
        *reinterpret_cast<uint4*>(mb + (size_t)node * FDIM + c * 8) = o;
    }
}

// ===================== MFMA GEMM: out = [mean|x] @ [Wl;Wr] + b (R9-proven) ============
template <bool RELU, bool OUTF32>
__global__ __launch_bounds__(256, 3)
void gemm_mfma_kernel(const short* __restrict__ Am, const short* Ax,
                      const short* __restrict__ Wt, const float* __restrict__ bias,
                      float* outf, short* outb, int n) {
    __shared__ short A_lds[64 * 256];   // 32 KB
    const int tid = threadIdx.x;
    const int w = tid >> 6, l = tid & 63;
    const int row0 = blockIdx.x * 64;

    s16x8 bfr[8][2];
    {
        const short* wb = Wt + ((32 * w + (l & 15)) * 256 + 8 * (l >> 4));
#pragma unroll
        for (int kc = 0; kc < 8; ++kc)
#pragma unroll
            for (int cf = 0; cf < 2; ++cf)
                bfr[kc][cf] = *reinterpret_cast<const s16x8*>(wb + cf * 16 * 256 + kc * 32);
    }

#pragma unroll
    for (int i = 0; i < 8; ++i) {
        int c = tid + 256 * i;          // [0, 2048)
        int r = c >> 5;
        int ck = c & 31;
        int row = row0 + r;
        s16x8 v;
        if (row < n) {
            const short* sp = (ck < 16) ? (Am + (size_t)row * FDIM + ck * 8)
                                        : (Ax + (size_t)row * FDIM + (ck - 16) * 8);
            v = *reinterpret_cast<const s16x8*>(sp);
        } else {
#pragma unroll
            for (int j = 0; j < 8; ++j) v[j] = 0;
        }
        int byte = r * 512 + ((ck * 16) ^ ((r & 7) << 4));
        *reinterpret_cast<s16x8*>(reinterpret_cast<char*>(A_lds) + byte) = v;
    }
    __syncthreads();

    f32x4 acc[4][2];
    {
        float b0 = bias[32 * w + (l & 15)];
        float b1 = bias[32 * w + 16 + (l & 15)];
#pragma unroll
        for (int rf = 0; rf < 4; ++rf)
#pragma unroll
            for (int i = 0; i < 4; ++i) { acc[rf][0][i] = b0; acc[rf][1][i] = b1; }
    }

    const int arow = l & 15;
    const int aq16 = 16 * (l >> 4);
#pragma unroll
    for (int kc = 0; kc < 8; ++kc) {
        s16x8 afr[4];
#pragma unroll
        for (int rf = 0; rf < 4; ++rf) {
            int r = 16 * rf + arow;
            int kbyte = 64 * kc + aq16;
            int byte = r * 512 + (kbyte ^ ((r & 7) << 4));
            afr[rf] = *reinterpret_cast<const s16x8*>(reinterpret_cast<const char*>(A_lds) + byte);
        }
#pragma unroll
        for (int rf = 0; rf < 4; ++rf)
#pragma unroll
            for (int cf = 0; cf < 2; ++cf)
                acc[rf][cf] = __builtin_amdgcn_mfma_f32_16x16x32_bf16(afr[rf], bfr[kc][cf], acc[rf][cf], 0, 0, 0);
    }

    const int ocol = 32 * w + (l & 15);
    const int orow = 4 * (l >> 4);
#pragma unroll
    for (int rf = 0; rf < 4; ++rf)
#pragma unroll
        for (int cf = 0; cf < 2; ++cf)
#pragma unroll
            for (int i = 0; i < 4; ++i) {
                int row = row0 + 16 * rf + orow + i;
                if (row < n) {
                    float v = acc[rf][cf][i];
                    if (RELU) v = fmaxf(v, 0.0f);
                    if (OUTF32) outf[(size_t)row * FDIM + ocol + 16 * cf] = v;
                    else        outb[(size_t)row * FDIM + ocol + 16 * cf] = (short)f2bf(v);
                }
            }
}

// ===================== fallback: atomic scatter path (R2, proven) =====================
__global__ void degree_kernel(const int* __restrict__ dst, float* __restrict__ cnt, int E) {
    int e = blockIdx.x * blockDim.x + threadIdx.x;
    if (e < E) atomicAdd(&cnt[dst[e]], 1.0f);
}

__global__ void scatter_kernel(const float* __restrict__ x, const int* __restrict__ src,
                               const int* __restrict__ dst, float* __restrict__ msg, int E) {
    int gt = blockIdx.x * blockDim.x + threadIdx.x;
    int e = gt >> 6;
    int lane = gt & 63;
    if (e >= E) return;
    int s = src[e];
    int d = dst[e];
    float2 v = reinterpret_cast<const float2*>(x + (size_t)s * FDIM)[lane];
    float* md = msg + (size_t)d * FDIM + 2 * lane;
    atomicAdd(md, v.x);
    atomicAdd(md + 1, v.y);
}

template <bool RELU>
__global__ void gemm_kernel(const float* agg, const float* cnt,
                            const float* __restrict__ xin, const float* __restrict__ Wl,
                            const float* __restrict__ Wr, const float* __restrict__ bias,
                            float* out, int n) {
    const int ROWS = 16;
    __shared__ float m_s[ROWS][FDIM];
    __shared__ float x_s[ROWS][FDIM];
    int tid = threadIdx.x;
    int row0 = blockIdx.x * ROWS;
#pragma unroll
    for (int i = 0; i < 2; ++i) {
        int idx4 = tid + i * 256;
        int r = idx4 >> 5;
        int c4 = idx4 & 31;
        int row = row0 + r;
        if (row < n) {
            float inv = cnt ? 1.0f / fmaxf(cnt[row], 1.0f) : 1.0f;
            float4 mv = reinterpret_cast<const float4*>(agg + (size_t)row * FDIM)[c4];
            float4 xv = reinterpret_cast<const float4*>(xin + (size_t)row * FDIM)[c4];
            float* mp = &m_s[r][c4 * 4];
            mp[0] = mv.x * inv; mp[1] = mv.y * inv; mp[2] = mv.z * inv; mp[3] = mv.w * inv;
            float* xp = &x_s[r][c4 * 4];
            xp[0] = xv.x; xp[1] = xv.y; xp[2] = xv.z; xp[3] = xv.w;
        }
    }
    __syncthreads();
    int j = tid & 127;
    int rh = tid >> 7;
    float acc[8];
    float bj = bias[j];
#pragma unroll
    for (int r = 0; r < 8; ++r) acc[r] = bj;
#pragma unroll 4
    for (int k = 0; k < FDIM; ++k) {
        float wl = Wl[k * FDIM + j];
        float wr = Wr[k * FDIM + j];
#pragma unroll
        for (int r = 0; r < 8; ++r)
            acc[r] += m_s[rh * 8 + r][k] * wl + x_s[rh * 8 + r][k] * wr;
    }
#pragma unroll
    for (int r = 0; r < 8; ++r) {
        int row = row0 + rh * 8 + r;
        if (row < n) {
            float v = acc[r];
            if (RELU) v = fmaxf(v, 0.0f);
            out[(size_t)row * FDIM + j] = v;
        }
    }
}

extern "C" void kernel_launch(void* const* d_in, const int* in_sizes, int n_in,
                              void* d_out, int out_size, void* d_ws, size_t ws_size,
                              hipStream_t stream) {
    const float* x   = (const float*)d_in[0];
    const int*   ei  = (const int*)d_in[1];
    const float* Wl0 = (const float*)d_in[2];
    const float* Wr0 = (const float*)d_in[3];
    const float* b0  = (const float*)d_in[4];
    const float* Wl1 = (const float*)d_in[5];
    const float* Wr1 = (const float*)d_in[6];
    const float* b1  = (const float*)d_in[7];

    int N = in_sizes[0] / FDIM;   // 50000
    int E = in_sizes[1] / 2;      // 800000
    const int* src = ei;
    const int* dst = ei + E;

    size_t featBytes  = (size_t)N * FDIM * sizeof(float);   // 25.6 MB
    size_t featBytesB = (size_t)N * FDIM * sizeof(short);   // 12.8 MB
    int edgeBlocks = (E + 255) / 256;                       // 3125
    int M = NGRP * N;                                       // 400000
    int blocksA = (M + 1023) / 1024;                        // 391

    // ---- workspace layout (~29.1 MB; CSR temps overlay the dead mb region) ----
    const size_t o_rp   = 0x1000;                 // N+1 ints
    const size_t o_wt0  = 0x33000;                // 64 KB
    const size_t o_wt1  = 0x43000;                // 64 KB
    const size_t o_eid  = 0x53000;                // E ints (3.2 MB)
    const size_t o_xb   = 0x361000;               // N*128 bf16 (x, then h in-place)
    const size_t o_mb   = o_xb + featBytesB;      // N*128 bf16 (mean), overlays CSR temps
    const size_t need   = o_mb + featBytesB;      // ~29.14 MB
    const size_t s_degg  = o_mb + 0x0;            // M ints (ends 0x186A00)
    const size_t s_state = o_mb + 0x187000;       // blocksA unsigned (lookback descriptors)
    const size_t s_off   = o_mb + 0x18B000;       // M+1 ints
    const size_t s_cur   = o_mb + 0x312000;       // M ints
    const size_t s_eidt  = o_mb + 0x499000;       // E ints (ends ~8.0MB < 12.8MB)

    if (ws_size >= need) {
        int*      rp     = (int*)((char*)d_ws + o_rp);
        short*    Wt0    = (short*)((char*)d_ws + o_wt0);
        short*    Wt1    = (short*)((char*)d_ws + o_wt1);
        int*      eid    = (int*)((char*)d_ws + o_eid);
        short*    xb     = (short*)((char*)d_ws + o_xb);
        short*    mb     = (short*)((char*)d_ws + o_mb);
        int*      degg   = (int*)((char*)d_ws + s_degg);
        unsigned* state  = (unsigned*)((char*)d_ws + s_state);
        int*      off    = (int*)((char*)d_ws + s_off);
        int*      cursor = (int*)((char*)d_ws + s_cur);
        int*      eidt   = (int*)((char*)d_ws + s_eidt);
        float*    outF   = (float*)d_out;

        int n4x = N * FDIM / 4;                   // 1.6M float4
        int XB  = (n4x + 255) / 256;              // 6250
        int WB  = 256;                            // 65536/256
        int nz  = 0x18B000 / 16;                  // zero degg+state span (101,120 int4)

        // 1) zero degg + lookback state
        zero_kernel<<<(nz + 255) / 256, 256, 0, stream>>>((int4*)degg, nz);
        // 2) histogram (+ weight transpose rides along)
        hist8w_kernel<<<edgeBlocks + WB, 256, 0, stream>>>(dst, degg, E, N, edgeBlocks,
                                                           Wl0, Wr0, Wl1, Wr1, Wt0, Wt1);
        // 3) single-pass scan -> off + cursor
        scan_kernel<<<blocksA, 256, 0, stream>>>(degg, off, cursor, state, M, E);
        // 4) fill (+ x->bf16 conversion rides along)
        fill8x_kernel<<<edgeBlocks + XB, 256, 0, stream>>>(src, dst, cursor, eidt, E, N, edgeBlocks,
                                                           x, xb, n4x);
        // 5) merge (computes + writes rp inline)
        merge_kernel<<<(N + 1 + 255) / 256, 256, 0, stream>>>(off, eidt, rp, eid, N, E);

        int gatherBlocks = (N + 3) / 4;
        int gemmBlocks   = (N + 63) / 64;
        // layer 0: h(bf16, in-place over xb) = relu([mean|x] @ Wcat0 + b0)
        gather_kernel<<<gatherBlocks, 256, 0, stream>>>(xb, rp, eid, mb, N);
        gemm_mfma_kernel<true, false><<<gemmBlocks, 256, 0, stream>>>(mb, xb, Wt0, b0, nullptr, xb, N);
        // layer 1: out(f32) = [mean(h)|h] @ Wcat1 + b1
        gather_kernel<<<gatherBlocks, 256, 0, stream>>>(xb, rp, eid, mb, N);
        gemm_mfma_kernel<false, true><<<gemmBlocks, 256, 0, stream>>>(mb, xb, Wt1, b1, outF, nullptr, N);
    } else {
        // fallback: proven atomic path
        float* cnt = (float*)d_ws;
        float* h   = (float*)((char*)d_ws + (1 << 18));
        float* msg = (float*)d_out;
        int gemmBlocks = (N + 15) / 16;

        hipMemsetAsync(cnt, 0, (size_t)N * sizeof(float), stream);
        degree_kernel<<<edgeBlocks, 256, 0, stream>>>(dst, cnt, E);

        hipMemsetAsync(msg, 0, featBytes, stream);
        scatter_kernel<<<(E * 64 + 255) / 256, 256, 0, stream>>>(x, src, dst, msg, E);
        gemm_kernel<true><<<gemmBlocks, 256, 0, stream>>>(msg, cnt, x, Wl0, Wr0, b0, h, N);

        hipMemsetAsync(msg, 0, featBytes, stream);
        scatter_kernel<<<(E * 64 + 255) / 256, 256, 0, stream>>>(h, src, dst, msg, E);
        gemm_kernel<false><<<gemmBlocks, 256, 0, stream>>>(msg, cnt, h, Wl1, Wr1, b1, msg, N);
    }
}

// Round 11
// 203.425 us; speedup vs baseline: 1.0089x; 1.0089x over previous
//
#include <hip/hip_runtime.h>

#define FDIM 128
#define NGRP 8

typedef __attribute__((ext_vector_type(4))) float f32x4;
typedef __attribute__((ext_vector_type(8))) short s16x8;
typedef __attribute__((ext_vector_type(4))) short s16x4;

__device__ inline unsigned short f2bf(float f) {      // RNE f32->bf16
    unsigned u = __builtin_bit_cast(unsigned, f);
    u += 0x7FFFu + ((u >> 16) & 1u);
    return (unsigned short)(u >> 16);
}
__device__ inline float bflo(unsigned u) { return __builtin_bit_cast(float, u << 16); }
__device__ inline float bfhi(unsigned u) { return __builtin_bit_cast(float, u & 0xFFFF0000u); }

// ====== prologue: zero(degg+state) + x->bf16 + weight transpose (R9-proven placement) ======
__global__ void prologue_kernel(int4* __restrict__ z4, int nz,
                                const float* __restrict__ x, short* __restrict__ xb, int n4x,
                                const float* __restrict__ Wl0, const float* __restrict__ Wr0,
                                const float* __restrict__ Wl1, const float* __restrict__ Wr1,
                                short* __restrict__ Wt0, short* __restrict__ Wt1,
                                int ZB, int XB) {
    int bid = blockIdx.x;
    if (bid < ZB) {
        int i = bid * 256 + threadIdx.x;
        if (i < nz) z4[i] = make_int4(0, 0, 0, 0);
    } else if (bid < ZB + XB) {
        int i = (bid - ZB) * 256 + threadIdx.x;
        if (i < n4x) {
            float4 v = reinterpret_cast<const float4*>(x)[i];
            s16x4 o;
            o[0] = (short)f2bf(v.x); o[1] = (short)f2bf(v.y);
            o[2] = (short)f2bf(v.z); o[3] = (short)f2bf(v.w);
            reinterpret_cast<s16x4*>(xb)[i] = o;
        }
    } else {
        int g = (bid - ZB - XB) * 256 + threadIdx.x;   // [0, 65536)
        int n = g & 127;
        int k = (g >> 7) & 255;
        int layer = g >> 15;
        const float* Wl = layer ? Wl1 : Wl0;
        const float* Wr = layer ? Wr1 : Wr0;
        short* Wt = layer ? Wt1 : Wt0;
        float v = (k < 128) ? Wl[k * 128 + n] : Wr[(k - 128) * 128 + n];
        Wt[n * 256 + k] = (short)f2bf(v);
    }
}

// =============== XCD-sharded histogram (standalone — no streaming riders!) ===============
__global__ void hist8_kernel(const int* __restrict__ dst, int* __restrict__ degg, int E, int N) {
    int e = blockIdx.x * blockDim.x + threadIdx.x;
    if (e < E) atomicAdd(&degg[(blockIdx.x & 7) * N + dst[e]], 1);
}

// =============== single-pass exclusive scan, decoupled lookback (R10-proven) ===============
__global__ __launch_bounds__(256)
void scan_kernel(const int* __restrict__ in, int* __restrict__ out, int* __restrict__ cursor,
                 unsigned* __restrict__ state, int M, int E) {
    __shared__ int s[256];
    __shared__ int s_excl;
    const int bid = blockIdx.x;
    const int t = threadIdx.x;
    int base = bid * 1024 + t * 4;
    int4 v = make_int4(0, 0, 0, 0);
    if (base + 3 < M) v = *reinterpret_cast<const int4*>(in + base);
    else {
        if (base + 0 < M) v.x = in[base + 0];
        if (base + 1 < M) v.y = in[base + 1];
        if (base + 2 < M) v.z = in[base + 2];
    }
    int tsum = v.x + v.y + v.z + v.w;
    s[t] = tsum;
    __syncthreads();
    for (int o2 = 1; o2 < 256; o2 <<= 1) {
        int tt = (t >= o2) ? s[t - o2] : 0;
        __syncthreads();
        s[t] += tt;
        __syncthreads();
    }
    int total = s[255];
    int texcl = s[t] - tsum;

    if (t == 0) {
        unsigned w = ((bid == 0 ? 2u : 1u) << 30) | (unsigned)total;
        __hip_atomic_store(&state[bid], w, __ATOMIC_RELEASE, __HIP_MEMORY_SCOPE_AGENT);
    }
    if (t < 64) {
        int excl = 0;
        int j = bid - 1;
        while (j >= 0) {
            int idx = j - t;
            unsigned w = 0;
            if (idx >= 0) {
                do {
                    w = __hip_atomic_load(&state[idx], __ATOMIC_ACQUIRE, __HIP_MEMORY_SCOPE_AGENT);
                } while ((w >> 30) == 0u);
            }
            int val = (int)(w & 0x3FFFFFFFu);
            bool isPre = (idx >= 0) && ((w >> 30) == 2u);
            unsigned long long mask = __ballot(isPre);
            int contrib;
            if (mask) {
                int stop = __ffsll((unsigned long long)mask) - 1;
                contrib = (t <= stop) ? val : 0;
            } else {
                contrib = (idx >= 0) ? val : 0;
            }
            for (int o = 32; o > 0; o >>= 1) contrib += __shfl_down(contrib, o);
            excl += contrib;
            if (mask) break;
            j -= 64;
        }
        if (t == 0) {
            s_excl = excl;
            unsigned w = (2u << 30) | (unsigned)(excl + total);
            __hip_atomic_store(&state[bid], w, __ATOMIC_RELEASE, __HIP_MEMORY_SCOPE_AGENT);
        }
    }
    __syncthreads();
    int b = s_excl;

    int e0 = b + texcl;
    int4 o;
    o.x = e0; o.y = o.x + v.x; o.z = o.y + v.y; o.w = o.z + v.z;
    if (base + 3 < M) {
        *reinterpret_cast<int4*>(out + base) = o;
        *reinterpret_cast<int4*>(cursor + base) = o;
    } else {
#pragma unroll
        for (int j2 = 0; j2 < 3; ++j2) {
            int vv = (j2 == 0) ? o.x : (j2 == 1) ? o.y : o.z;
            if (base + j2 < M) { out[base + j2] = vv; cursor[base + j2] = vv; }
        }
    }
    if (bid == 0 && t == 0) out[M] = E;
}

// =============== XCD-sharded fill (standalone — no streaming riders!) ===============
__global__ void fill8_kernel(const int* __restrict__ src, const int* __restrict__ dst,
                             int* __restrict__ cursor, int* __restrict__ eidt, int E, int N) {
    int e = blockIdx.x * blockDim.x + threadIdx.x;
    if (e < E) {
        int p = atomicAdd(&cursor[(blockIdx.x & 7) * N + dst[e]], 1);
        eidt[p] = src[e];
    }
}

// =============== merge 8 group-runs -> dense eid; computes+writes rp inline (R10-proven) =====
__global__ void merge_kernel(const int* __restrict__ off, const int* __restrict__ eidt,
                             int* __restrict__ rp, int* __restrict__ eid, int N, int E) {
    __shared__ int S0;
    if (threadIdx.x == 0) {
        int s = 0;
#pragma unroll
        for (int g = 0; g < NGRP; ++g) s += off[g * N];
        S0 = s;
    }
    __syncthreads();
    int i = blockIdx.x * 256 + threadIdx.x;
    if (i > N) return;
    if (i == N) { rp[N] = E; return; }
    int bs[NGRP], es[NGRP];
    int si = 0;
#pragma unroll
    for (int g = 0; g < NGRP; ++g) {
        bs[g] = off[g * N + i];
        es[g] = off[g * N + i + 1];
        si += bs[g];
    }
    int dp = si - S0;
    rp[i] = dp;
#pragma unroll
    for (int g = 0; g < NGRP; ++g)
        for (int k = bs[g]; k < es[g]; ++k) eid[dp++] = eidt[k];
}

// ============ gather v3: 16 neighbor rows in flight per iteration (R9-proven) ============
#define ACC8(v) { a[0]+=bflo(v.x); a[1]+=bfhi(v.x); a[2]+=bflo(v.y); a[3]+=bfhi(v.y); \
                  a[4]+=bflo(v.z); a[5]+=bfhi(v.z); a[6]+=bflo(v.w); a[7]+=bfhi(v.w); }

__global__ void gather_kernel(const short* __restrict__ X, const int* __restrict__ rp,
                              const int* __restrict__ eid, short* __restrict__ mb, int N) {
    int node = blockIdx.x * (blockDim.x >> 6) + (threadIdx.x >> 6);
    int lane = threadIdx.x & 63;
    int g = lane >> 4;
    int c = lane & 15;
    if (node >= N) return;
    int beg = rp[node], end = rp[node + 1];
    float a[8];
#pragma unroll
    for (int j = 0; j < 8; ++j) a[j] = 0.0f;

    int k = beg;
    for (; k + 16 <= end; k += 16) {
        int s0 = eid[k + g];
        int s1 = eid[k + 4 + g];
        int s2 = eid[k + 8 + g];
        int s3 = eid[k + 12 + g];
        uint4 v0 = *reinterpret_cast<const uint4*>(X + (size_t)s0 * FDIM + c * 8);
        uint4 v1 = *reinterpret_cast<const uint4*>(X + (size_t)s1 * FDIM + c * 8);
        uint4 v2 = *reinterpret_cast<const uint4*>(X + (size_t)s2 * FDIM + c * 8);
        uint4 v3 = *reinterpret_cast<const uint4*>(X + (size_t)s3 * FDIM + c * 8);
        ACC8(v0); ACC8(v1); ACC8(v2); ACC8(v3);
    }
    if (k + 8 <= end) {
        int s0 = eid[k + g];
        int s1 = eid[k + 4 + g];
        uint4 v0 = *reinterpret_cast<const uint4*>(X + (size_t)s0 * FDIM + c * 8);
        uint4 v1 = *reinterpret_cast<const uint4*>(X + (size_t)s1 * FDIM + c * 8);
        ACC8(v0); ACC8(v1);
        k += 8;
    }
    if (k + 4 <= end) {
        int s0 = eid[k + g];
        uint4 v0 = *reinterpret_cast<const uint4*>(X + (size_t)s0 * FDIM + c * 8);
        ACC8(v0);
        k += 4;
    }
    int rem = end - k;                        // 0..3
    if (g < rem) {
        int s0 = eid[k + g];
        uint4 v0 = *reinterpret_cast<const uint4*>(X + (size_t)s0 * FDIM + c * 8);
        ACC8(v0);
    }

#pragma unroll
    for (int j = 0; j < 8; ++j) a[j] += __shfl_xor(a[j], 16);
#pragma unroll
    for (int j = 0; j < 8; ++j) a[j] += __shfl_xor(a[j], 32);

    if (g == 0) {
        float inv = (end > beg) ? 1.0f / (float)(end - beg) : 0.0f;
        uint4 o;
        o.x = (unsigned)f2bf(a[0] * inv) | ((unsigned)f2bf(a[1] * inv) << 16);
        o.y = (unsigned)f2bf(a[2] * inv) | ((unsigned)f2bf(a[3] * inv) << 16);
        o.z = (unsigned)f2bf(a[4] * inv) | ((unsigned)f2bf(a[5] * inv) << 16);
        o.w = (unsigned)f2bf(a[6] * inv) | ((unsigned)f2bf(a[7] * inv) << 16);
        *reinterpret_cast<uint4*>(mb + (size_t)node * FDIM + c * 8) = o;
    }
}

// ===================== MFMA GEMM: out = [mean|x] @ [Wl;Wr] + b (R9-proven) ============
template <bool RELU, bool OUTF32>
__global__ __launch_bounds__(256, 3)
void gemm_mfma_kernel(const short* __restrict__ Am, const short* Ax,
                      const short* __restrict__ Wt, const float* __restrict__ bias,
                      float* outf, short* outb, int n) {
    __shared__ short A_lds[64 * 256];   // 32 KB
    const int tid = threadIdx.x;
    const int w = tid >> 6, l = tid & 63;
    const int row0 = blockIdx.x * 64;

    s16x8 bfr[8][2];
    {
        const short* wb = Wt + ((32 * w + (l & 15)) * 256 + 8 * (l >> 4));
#pragma unroll
        for (int kc = 0; kc < 8; ++kc)
#pragma unroll
            for (int cf = 0; cf < 2; ++cf)
                bfr[kc][cf] = *reinterpret_cast<const s16x8*>(wb + cf * 16 * 256 + kc * 32);
    }

#pragma unroll
    for (int i = 0; i < 8; ++i) {
        int c = tid + 256 * i;          // [0, 2048)
        int r = c >> 5;
        int ck = c & 31;
        int row = row0 + r;
        s16x8 v;
        if (row < n) {
            const short* sp = (ck < 16) ? (Am + (size_t)row * FDIM + ck * 8)
                                        : (Ax + (size_t)row * FDIM + (ck - 16) * 8);
            v = *reinterpret_cast<const s16x8*>(sp);
        } else {
#pragma unroll
            for (int j = 0; j < 8; ++j) v[j] = 0;
        }
        int byte = r * 512 + ((ck * 16) ^ ((r & 7) << 4));
        *reinterpret_cast<s16x8*>(reinterpret_cast<char*>(A_lds) + byte) = v;
    }
    __syncthreads();

    f32x4 acc[4][2];
    {
        float b0 = bias[32 * w + (l & 15)];
        float b1 = bias[32 * w + 16 + (l & 15)];
#pragma unroll
        for (int rf = 0; rf < 4; ++rf)
#pragma unroll
            for (int i = 0; i < 4; ++i) { acc[rf][0][i] = b0; acc[rf][1][i] = b1; }
    }

    const int arow = l & 15;
    const int aq16 = 16 * (l >> 4);
#pragma unroll
    for (int kc = 0; kc < 8; ++kc) {
        s16x8 afr[4];
#pragma unroll
        for (int rf = 0; rf < 4; ++rf) {
            int r = 16 * rf + arow;
            int kbyte = 64 * kc + aq16;
            int byte = r * 512 + (kbyte ^ ((r & 7) << 4));
            afr[rf] = *reinterpret_cast<const s16x8*>(reinterpret_cast<const char*>(A_lds) + byte);
        }
#pragma unroll
        for (int rf = 0; rf < 4; ++rf)
#pragma unroll
            for (int cf = 0; cf < 2; ++cf)
                acc[rf][cf] = __builtin_amdgcn_mfma_f32_16x16x32_bf16(afr[rf], bfr[kc][cf], acc[rf][cf], 0, 0, 0);
    }

    const int ocol = 32 * w + (l & 15);
    const int orow = 4 * (l >> 4);
#pragma unroll
    for (int rf = 0; rf < 4; ++rf)
#pragma unroll
        for (int cf = 0; cf < 2; ++cf)
#pragma unroll
            for (int i = 0; i < 4; ++i) {
                int row = row0 + 16 * rf + orow + i;
                if (row < n) {
                    float v = acc[rf][cf][i];
                    if (RELU) v = fmaxf(v, 0.0f);
                    if (OUTF32) outf[(size_t)row * FDIM + ocol + 16 * cf] = v;
                    else        outb[(size_t)row * FDIM + ocol + 16 * cf] = (short)f2bf(v);
                }
            }
}

// ===================== fallback: atomic scatter path (R2, proven) =====================
__global__ void degree_kernel(const int* __restrict__ dst, float* __restrict__ cnt, int E) {
    int e = blockIdx.x * blockDim.x + threadIdx.x;
    if (e < E) atomicAdd(&cnt[dst[e]], 1.0f);
}

__global__ void scatter_kernel(const float* __restrict__ x, const int* __restrict__ src,
                               const int* __restrict__ dst, float* __restrict__ msg, int E) {
    int gt = blockIdx.x * blockDim.x + threadIdx.x;
    int e = gt >> 6;
    int lane = gt & 63;
    if (e >= E) return;
    int s = src[e];
    int d = dst[e];
    float2 v = reinterpret_cast<const float2*>(x + (size_t)s * FDIM)[lane];
    float* md = msg + (size_t)d * FDIM + 2 * lane;
    atomicAdd(md, v.x);
    atomicAdd(md + 1, v.y);
}

template <bool RELU>
__global__ void gemm_kernel(const float* agg, const float* cnt,
                            const float* __restrict__ xin, const float* __restrict__ Wl,
                            const float* __restrict__ Wr, const float* __restrict__ bias,
                            float* out, int n) {
    const int ROWS = 16;
    __shared__ float m_s[ROWS][FDIM];
    __shared__ float x_s[ROWS][FDIM];
    int tid = threadIdx.x;
    int row0 = blockIdx.x * ROWS;
#pragma unroll
    for (int i = 0; i < 2; ++i) {
        int idx4 = tid + i * 256;
        int r = idx4 >> 5;
        int c4 = idx4 & 31;
        int row = row0 + r;
        if (row < n) {
            float inv = cnt ? 1.0f / fmaxf(cnt[row], 1.0f) : 1.0f;
            float4 mv = reinterpret_cast<const float4*>(agg + (size_t)row * FDIM)[c4];
            float4 xv = reinterpret_cast<const float4*>(xin + (size_t)row * FDIM)[c4];
            float* mp = &m_s[r][c4 * 4];
            mp[0] = mv.x * inv; mp[1] = mv.y * inv; mp[2] = mv.z * inv; mp[3] = mv.w * inv;
            float* xp = &x_s[r][c4 * 4];
            xp[0] = xv.x; xp[1] = xv.y; xp[2] = xv.z; xp[3] = xv.w;
        }
    }
    __syncthreads();
    int j = tid & 127;
    int rh = tid >> 7;
    float acc[8];
    float bj = bias[j];
#pragma unroll
    for (int r = 0; r < 8; ++r) acc[r] = bj;
#pragma unroll 4
    for (int k = 0; k < FDIM; ++k) {
        float wl = Wl[k * FDIM + j];
        float wr = Wr[k * FDIM + j];
#pragma unroll
        for (int r = 0; r < 8; ++r)
            acc[r] += m_s[rh * 8 + r][k] * wl + x_s[rh * 8 + r][k] * wr;
    }
#pragma unroll
    for (int r = 0; r < 8; ++r) {
        int row = row0 + rh * 8 + r;
        if (row < n) {
            float v = acc[r];
            if (RELU) v = fmaxf(v, 0.0f);
            out[(size_t)row * FDIM + j] = v;
        }
    }
}

extern "C" void kernel_launch(void* const* d_in, const int* in_sizes, int n_in,
                              void* d_out, int out_size, void* d_ws, size_t ws_size,
                              hipStream_t stream) {
    const float* x   = (const float*)d_in[0];
    const int*   ei  = (const int*)d_in[1];
    const float* Wl0 = (const float*)d_in[2];
    const float* Wr0 = (const float*)d_in[3];
    const float* b0  = (const float*)d_in[4];
    const float* Wl1 = (const float*)d_in[5];
    const float* Wr1 = (const float*)d_in[6];
    const float* b1  = (const float*)d_in[7];

    int N = in_sizes[0] / FDIM;   // 50000
    int E = in_sizes[1] / 2;      // 800000
    const int* src = ei;
    const int* dst = ei + E;

    size_t featBytes  = (size_t)N * FDIM * sizeof(float);   // 25.6 MB
    size_t featBytesB = (size_t)N * FDIM * sizeof(short);   // 12.8 MB
    int edgeBlocks = (E + 255) / 256;                       // 3125
    int M = NGRP * N;                                       // 400000
    int blocksA = (M + 1023) / 1024;                        // 391

    // ---- workspace layout (~29.1 MB; CSR temps overlay the dead mb region) ----
    const size_t o_rp   = 0x1000;                 // N+1 ints
    const size_t o_wt0  = 0x33000;                // 64 KB
    const size_t o_wt1  = 0x43000;                // 64 KB
    const size_t o_eid  = 0x53000;                // E ints (3.2 MB)
    const size_t o_xb   = 0x361000;               // N*128 bf16 (x, then h in-place)
    const size_t o_mb   = o_xb + featBytesB;      // N*128 bf16 (mean), overlays CSR temps
    const size_t need   = o_mb + featBytesB;      // ~29.14 MB
    const size_t s_degg  = o_mb + 0x0;            // M ints (ends 0x186A00)
    const size_t s_state = o_mb + 0x187000;       // blocksA unsigned (lookback descriptors)
    const size_t s_off   = o_mb + 0x18B000;       // M+1 ints
    const size_t s_cur   = o_mb + 0x312000;       // M ints
    const size_t s_eidt  = o_mb + 0x499000;       // E ints (ends ~8.0MB < 12.8MB)

    if (ws_size >= need) {
        int*      rp     = (int*)((char*)d_ws + o_rp);
        short*    Wt0    = (short*)((char*)d_ws + o_wt0);
        short*    Wt1    = (short*)((char*)d_ws + o_wt1);
        int*      eid    = (int*)((char*)d_ws + o_eid);
        short*    xb     = (short*)((char*)d_ws + o_xb);
        short*    mb     = (short*)((char*)d_ws + o_mb);
        int*      degg   = (int*)((char*)d_ws + s_degg);
        unsigned* state  = (unsigned*)((char*)d_ws + s_state);
        int*      off    = (int*)((char*)d_ws + s_off);
        int*      cursor = (int*)((char*)d_ws + s_cur);
        int*      eidt   = (int*)((char*)d_ws + s_eidt);
        float*    outF   = (float*)d_out;

        int n4x = N * FDIM / 4;                   // 1.6M float4
        int nz  = 0x18B000 / 16;                  // zero degg+state span (101,120 int4)
        int ZB  = (nz + 255) / 256;               // 396
        int XB  = (n4x + 255) / 256;              // 6250
        int WB  = 256;                            // 65536/256

        // 1) prologue: zero(degg+state) + x->bf16 + weight transpose
        prologue_kernel<<<ZB + XB + WB, 256, 0, stream>>>(
            (int4*)degg, nz, x, xb, n4x, Wl0, Wr0, Wl1, Wr1, Wt0, Wt1, ZB, XB);
        // 2) histogram (standalone: no cache-polluting riders with the atomics)
        hist8_kernel<<<edgeBlocks, 256, 0, stream>>>(dst, degg, E, N);
        // 3) single-pass lookback scan -> off + cursor
        scan_kernel<<<blocksA, 256, 0, stream>>>(degg, off, cursor, state, M, E);
        // 4) fill (standalone, L2-local cursors)
        fill8_kernel<<<edgeBlocks, 256, 0, stream>>>(src, dst, cursor, eidt, E, N);
        // 5) merge (computes + writes rp inline)
        merge_kernel<<<(N + 1 + 255) / 256, 256, 0, stream>>>(off, eidt, rp, eid, N, E);

        int gatherBlocks = (N + 3) / 4;
        int gemmBlocks   = (N + 63) / 64;
        // layer 0: h(bf16, in-place over xb) = relu([mean|x] @ Wcat0 + b0)
        gather_kernel<<<gatherBlocks, 256, 0, stream>>>(xb, rp, eid, mb, N);
        gemm_mfma_kernel<true, false><<<gemmBlocks, 256, 0, stream>>>(mb, xb, Wt0, b0, nullptr, xb, N);
        // layer 1: out(f32) = [mean(h)|h] @ Wcat1 + b1
        gather_kernel<<<gatherBlocks, 256, 0, stream>>>(xb, rp, eid, mb, N);
        gemm_mfma_kernel<false, true><<<gemmBlocks, 256, 0, stream>>>(mb, xb, Wt1, b1, outF, nullptr, N);
    } else {
        // fallback: proven atomic path
        float* cnt = (float*)d_ws;
        float* h   = (float*)((char*)d_ws + (1 << 18));
        float* msg = (float*)d_out;
        int gemmBlocks = (N + 15) / 16;

        hipMemsetAsync(cnt, 0, (size_t)N * sizeof(float), stream);
        degree_kernel<<<edgeBlocks, 256, 0, stream>>>(dst, cnt, E);

        hipMemsetAsync(msg, 0, featBytes, stream);
        scatter_kernel<<<(E * 64 + 255) / 256, 256, 0, stream>>>(x, src, dst, msg, E);
        gemm_kernel<true><<<gemmBlocks, 256, 0, stream>>>(msg, cnt, x, Wl0, Wr0, b0, h, N);

        hipMemsetAsync(msg, 0, featBytes, stream);
        scatter_kernel<<<(E * 64 + 255) / 256, 256, 0, stream>>>(h, src, dst, msg, E);
        gemm_kernel<false><<<gemmBlocks, 256, 0, stream>>>(msg, cnt, h, Wl1, Wr1, b1, msg, N);
    }
}

// Round 12
// 188.709 us; speedup vs baseline: 1.0876x; 1.0780x over previous
//
#include <hip/hip_runtime.h>

#define FDIM 128
#define NGRP 8

typedef __attribute__((ext_vector_type(4))) float f32x4;
typedef __attribute__((ext_vector_type(8))) short s16x8;
typedef __attribute__((ext_vector_type(4))) short s16x4;

__device__ inline unsigned short f2bf(float f) {      // RNE f32->bf16
    unsigned u = __builtin_bit_cast(unsigned, f);
    u += 0x7FFFu + ((u >> 16) & 1u);
    return (unsigned short)(u >> 16);
}
__device__ inline float bflo(unsigned u) { return __builtin_bit_cast(float, u << 16); }
__device__ inline float bfhi(unsigned u) { return __builtin_bit_cast(float, u & 0xFFFF0000u); }

// =============== prologue: zero(degg) + prep_x + prep_w in ONE kernel (R9-proven) ===============
__global__ void prologue_kernel(int4* __restrict__ degg4, int nz,
                                const float* __restrict__ x, short* __restrict__ xb, int n4x,
                                const float* __restrict__ Wl0, const float* __restrict__ Wr0,
                                const float* __restrict__ Wl1, const float* __restrict__ Wr1,
                                short* __restrict__ Wt0, short* __restrict__ Wt1,
                                int ZB, int XB) {
    int bid = blockIdx.x;
    if (bid < ZB) {
        int i = bid * 256 + threadIdx.x;
        if (i < nz) degg4[i] = make_int4(0, 0, 0, 0);
    } else if (bid < ZB + XB) {
        int i = (bid - ZB) * 256 + threadIdx.x;
        if (i < n4x) {
            float4 v = reinterpret_cast<const float4*>(x)[i];
            s16x4 o;
            o[0] = (short)f2bf(v.x); o[1] = (short)f2bf(v.y);
            o[2] = (short)f2bf(v.z); o[3] = (short)f2bf(v.w);
            reinterpret_cast<s16x4*>(xb)[i] = o;
        }
    } else {
        int g = (bid - ZB - XB) * 256 + threadIdx.x;   // [0, 65536)
        int n = g & 127;
        int k = (g >> 7) & 255;
        int layer = g >> 15;
        const float* Wl = layer ? Wl1 : Wl0;
        const float* Wr = layer ? Wr1 : Wr0;
        short* Wt = layer ? Wt1 : Wt0;
        float v = (k < 128) ? Wl[k * 128 + n] : Wr[(k - 128) * 128 + n];
        Wt[n * 256 + k] = (short)f2bf(v);
    }
}

// =============== XCD-sharded CSR build (R7/R9-proven) ===============
__global__ void hist8_kernel(const int* __restrict__ dst, int* __restrict__ degg, int E, int N) {
    int e = blockIdx.x * blockDim.x + threadIdx.x;
    if (e < E) atomicAdd(&degg[(blockIdx.x & 7) * N + dst[e]], 1);
}

// flat exclusive scan over M=8N elems, 4 elems/thread (1024/block); block totals to bsum
__global__ void scanA1_kernel(const int* __restrict__ in, int* __restrict__ out,
                              int* __restrict__ bsum, int M) {
    __shared__ int s[256];
    int base = blockIdx.x * 1024 + threadIdx.x * 4;
    int4 v = make_int4(0, 0, 0, 0);
    if (base + 3 < M) v = *reinterpret_cast<const int4*>(in + base);
    else {
        if (base + 0 < M) v.x = in[base + 0];
        if (base + 1 < M) v.y = in[base + 1];
        if (base + 2 < M) v.z = in[base + 2];
        if (base + 3 < M) v.w = in[base + 3];
    }
    int tsum = v.x + v.y + v.z + v.w;
    s[threadIdx.x] = tsum;
    __syncthreads();
    for (int off = 1; off < 256; off <<= 1) {
        int t = (threadIdx.x >= off) ? s[threadIdx.x - off] : 0;
        __syncthreads();
        s[threadIdx.x] += t;
        __syncthreads();
    }
    int excl = s[threadIdx.x] - tsum;
    int4 o;
    o.x = excl; o.y = excl + v.x; o.z = o.y + v.y; o.w = o.z + v.z;
    if (base + 3 < M) *reinterpret_cast<int4*>(out + base) = o;
    else {
        if (base + 0 < M) out[base + 0] = o.x;
        if (base + 1 < M) out[base + 1] = o.y;
        if (base + 2 < M) out[base + 2] = o.z;
    }
    if (threadIdx.x == 255) bsum[blockIdx.x] = s[255];
}

// scanA3 v2: folds the bsum prefix-scan in (each block reduces bsum[0..bid) itself).
// Requires nb <= 512 (nb = 391 here).
__global__ void scanA3_kernel(int* __restrict__ off, int* __restrict__ cursor,
                              const int* __restrict__ bsum, int nb, int M, int E) {
    __shared__ int s[256];
    int t = threadIdx.x;
    int v = 0;
    if (t < blockIdx.x) v += bsum[t];
    if (t + 256 < blockIdx.x) v += bsum[t + 256];
    s[t] = v;
    __syncthreads();
    for (int off2 = 128; off2 > 0; off2 >>= 1) {
        if (t < off2) s[t] += s[t + off2];
        __syncthreads();
    }
    int b = s[0];   // exclusive prefix of block sums for this block

    int base = blockIdx.x * 1024 + t * 4;
    if (base + 3 < M) {
        int4 w = *reinterpret_cast<const int4*>(off + base);
        w.x += b; w.y += b; w.z += b; w.w += b;
        *reinterpret_cast<int4*>(off + base) = w;
        *reinterpret_cast<int4*>(cursor + base) = w;
    } else {
#pragma unroll
        for (int j = 0; j < 4; ++j)
            if (base + j < M) { int q = off[base + j] + b; off[base + j] = q; cursor[base + j] = q; }
    }
    if (base == 0) off[M] = E;
}

// rp[i] = sum_g off[g*N+i] - sum_g off[g*N]   (constant-base trick)
__global__ void rp_kernel(const int* __restrict__ off, int* __restrict__ rp, int N, int E) {
    __shared__ int S0;
    if (threadIdx.x == 0) {
        int s = 0;
#pragma unroll
        for (int g = 0; g < NGRP; ++g) s += off[g * N];
        S0 = s;
    }
    __syncthreads();
    int i = blockIdx.x * 256 + threadIdx.x;
    if (i < N) {
        int s = 0;
#pragma unroll
        for (int g = 0; g < NGRP; ++g) s += off[g * N + i];
        rp[i] = s - S0;
    } else if (i == N) {
        rp[N] = E;
    }
}

__global__ void fill8_kernel(const int* __restrict__ src, const int* __restrict__ dst,
                             int* __restrict__ cursor, int* __restrict__ eidt, int E, int N) {
    int e = blockIdx.x * blockDim.x + threadIdx.x;
    if (e < E) {
        int p = atomicAdd(&cursor[(blockIdx.x & 7) * N + dst[e]], 1);
        eidt[p] = src[e];
    }
}

// per-node: concatenate the 8 group-runs into the final dense eid
__global__ void merge_kernel(const int* __restrict__ off, const int* __restrict__ eidt,
                             const int* __restrict__ rp, int* __restrict__ eid, int N) {
    int i = blockIdx.x * 256 + threadIdx.x;
    if (i >= N) return;
    int dp = rp[i];
#pragma unroll
    for (int g = 0; g < NGRP; ++g) {
        int b = off[g * N + i];
        int e2 = off[g * N + i + 1];
        for (int k = b; k < e2; ++k) eid[dp++] = eidt[k];
    }
}

// ============ gather v3: 16 neighbor rows in flight per iteration (R9-proven) ============
#define ACC8(v) { a[0]+=bflo(v.x); a[1]+=bfhi(v.x); a[2]+=bflo(v.y); a[3]+=bfhi(v.y); \
                  a[4]+=bflo(v.z); a[5]+=bfhi(v.z); a[6]+=bflo(v.w); a[7]+=bfhi(v.w); }

__global__ void gather_kernel(const short* __restrict__ X, const int* __restrict__ rp,
                              const int* __restrict__ eid, short* __restrict__ mb, int N) {
    int node = blockIdx.x * (blockDim.x >> 6) + (threadIdx.x >> 6);
    int lane = threadIdx.x & 63;
    int g = lane >> 4;
    int c = lane & 15;
    if (node >= N) return;
    int beg = rp[node], end = rp[node + 1];
    float a[8];
#pragma unroll
    for (int j = 0; j < 8; ++j) a[j] = 0.0f;

    int k = beg;
    for (; k + 16 <= end; k += 16) {          // 4 independent 4-row batches in flight
        int s0 = eid[k + g];
        int s1 = eid[k + 4 + g];
        int s2 = eid[k + 8 + g];
        int s3 = eid[k + 12 + g];
        uint4 v0 = *reinterpret_cast<const uint4*>(X + (size_t)s0 * FDIM + c * 8);
        uint4 v1 = *reinterpret_cast<const uint4*>(X + (size_t)s1 * FDIM + c * 8);
        uint4 v2 = *reinterpret_cast<const uint4*>(X + (size_t)s2 * FDIM + c * 8);
        uint4 v3 = *reinterpret_cast<const uint4*>(X + (size_t)s3 * FDIM + c * 8);
        ACC8(v0); ACC8(v1); ACC8(v2); ACC8(v3);
    }
    if (k + 8 <= end) {
        int s0 = eid[k + g];
        int s1 = eid[k + 4 + g];
        uint4 v0 = *reinterpret_cast<const uint4*>(X + (size_t)s0 * FDIM + c * 8);
        uint4 v1 = *reinterpret_cast<const uint4*>(X + (size_t)s1 * FDIM + c * 8);
        ACC8(v0); ACC8(v1);
        k += 8;
    }
    if (k + 4 <= end) {
        int s0 = eid[k + g];
        uint4 v0 = *reinterpret_cast<const uint4*>(X + (size_t)s0 * FDIM + c * 8);
        ACC8(v0);
        k += 4;
    }
    int rem = end - k;                        // 0..3
    if (g < rem) {
        int s0 = eid[k + g];
        uint4 v0 = *reinterpret_cast<const uint4*>(X + (size_t)s0 * FDIM + c * 8);
        ACC8(v0);
    }

#pragma unroll
    for (int j = 0; j < 8; ++j) a[j] += __shfl_xor(a[j], 16);
#pragma unroll
    for (int j = 0; j < 8; ++j) a[j] += __shfl_xor(a[j], 32);

    if (g == 0) {
        float inv = (end > beg) ? 1.0f / (float)(end - beg) : 0.0f;
        uint4 o;
        o.x = (unsigned)f2bf(a[0] * inv) | ((unsigned)f2bf(a[1] * inv) << 16);
        o.y = (unsigned)f2bf(a[2] * inv) | ((unsigned)f2bf(a[3] * inv) << 16);
        o.z = (unsigned)f2bf(a[4] * inv) | ((unsigned)f2bf(a[5] * inv) << 16);
        o.w = (unsigned)f2bf(a[6] * inv) | ((unsigned)f2bf(a[7] * inv) << 16);
        *reinterpret_cast<uint4*>(mb + (size_t)node * FDIM + c * 8) = o;
    }
}

// ===================== MFMA GEMM: out = [mean|x] @ [Wl;Wr] + b (R9-proven) ============
template <bool RELU, bool OUTF32>
__global__ __launch_bounds__(256, 3)
void gemm_mfma_kernel(const short* __restrict__ Am, const short* Ax,
                      const short* __restrict__ Wt, const float* __restrict__ bias,
                      float* outf, short* outb, int n) {
    __shared__ short A_lds[64 * 256];   // 32 KB
    const int tid = threadIdx.x;
    const int w = tid >> 6, l = tid & 63;
    const int row0 = blockIdx.x * 64;

    s16x8 bfr[8][2];
    {
        const short* wb = Wt + ((32 * w + (l & 15)) * 256 + 8 * (l >> 4));
#pragma unroll
        for (int kc = 0; kc < 8; ++kc)
#pragma unroll
            for (int cf = 0; cf < 2; ++cf)
                bfr[kc][cf] = *reinterpret_cast<const s16x8*>(wb + cf * 16 * 256 + kc * 32);
    }

#pragma unroll
    for (int i = 0; i < 8; ++i) {
        int c = tid + 256 * i;          // [0, 2048)
        int r = c >> 5;
        int ck = c & 31;
        int row = row0 + r;
        s16x8 v;
        if (row < n) {
            const short* sp = (ck < 16) ? (Am + (size_t)row * FDIM + ck * 8)
                                        : (Ax + (size_t)row * FDIM + (ck - 16) * 8);
            v = *reinterpret_cast<const s16x8*>(sp);
        } else {
#pragma unroll
            for (int j = 0; j < 8; ++j) v[j] = 0;
        }
        int byte = r * 512 + ((ck * 16) ^ ((r & 7) << 4));
        *reinterpret_cast<s16x8*>(reinterpret_cast<char*>(A_lds) + byte) = v;
    }
    __syncthreads();

    f32x4 acc[4][2];
    {
        float b0 = bias[32 * w + (l & 15)];
        float b1 = bias[32 * w + 16 + (l & 15)];
#pragma unroll
        for (int rf = 0; rf < 4; ++rf)
#pragma unroll
            for (int i = 0; i < 4; ++i) { acc[rf][0][i] = b0; acc[rf][1][i] = b1; }
    }

    const int arow = l & 15;
    const int aq16 = 16 * (l >> 4);
#pragma unroll
    for (int kc = 0; kc < 8; ++kc) {
        s16x8 afr[4];
#pragma unroll
        for (int rf = 0; rf < 4; ++rf) {
            int r = 16 * rf + arow;
            int kbyte = 64 * kc + aq16;
            int byte = r * 512 + (kbyte ^ ((r & 7) << 4));
            afr[rf] = *reinterpret_cast<const s16x8*>(reinterpret_cast<const char*>(A_lds) + byte);
        }
#pragma unroll
        for (int rf = 0; rf < 4; ++rf)
#pragma unroll
            for (int cf = 0; cf < 2; ++cf)
                acc[rf][cf] = __builtin_amdgcn_mfma_f32_16x16x32_bf16(afr[rf], bfr[kc][cf], acc[rf][cf], 0, 0, 0);
    }

    const int ocol = 32 * w + (l & 15);
    const int orow = 4 * (l >> 4);
#pragma unroll
    for (int rf = 0; rf < 4; ++rf)
#pragma unroll
        for (int cf = 0; cf < 2; ++cf)
#pragma unroll
            for (int i = 0; i < 4; ++i) {
                int row = row0 + 16 * rf + orow + i;
                if (row < n) {
                    float v = acc[rf][cf][i];
                    if (RELU) v = fmaxf(v, 0.0f);
                    if (OUTF32) outf[(size_t)row * FDIM + ocol + 16 * cf] = v;
                    else        outb[(size_t)row * FDIM + ocol + 16 * cf] = (short)f2bf(v);
                }
            }
}

// ===================== fallback: atomic scatter path (R2, proven) =====================
__global__ void degree_kernel(const int* __restrict__ dst, float* __restrict__ cnt, int E) {
    int e = blockIdx.x * blockDim.x + threadIdx.x;
    if (e < E) atomicAdd(&cnt[dst[e]], 1.0f);
}

__global__ void scatter_kernel(const float* __restrict__ x, const int* __restrict__ src,
                               const int* __restrict__ dst, float* __restrict__ msg, int E) {
    int gt = blockIdx.x * blockDim.x + threadIdx.x;
    int e = gt >> 6;
    int lane = gt & 63;
    if (e >= E) return;
    int s = src[e];
    int d = dst[e];
    float2 v = reinterpret_cast<const float2*>(x + (size_t)s * FDIM)[lane];
    float* md = msg + (size_t)d * FDIM + 2 * lane;
    atomicAdd(md, v.x);
    atomicAdd(md + 1, v.y);
}

template <bool RELU>
__global__ void gemm_kernel(const float* agg, const float* cnt,
                            const float* __restrict__ xin, const float* __restrict__ Wl,
                            const float* __restrict__ Wr, const float* __restrict__ bias,
                            float* out, int n) {
    const int ROWS = 16;
    __shared__ float m_s[ROWS][FDIM];
    __shared__ float x_s[ROWS][FDIM];
    int tid = threadIdx.x;
    int row0 = blockIdx.x * ROWS;
#pragma unroll
    for (int i = 0; i < 2; ++i) {
        int idx4 = tid + i * 256;
        int r = idx4 >> 5;
        int c4 = idx4 & 31;
        int row = row0 + r;
        if (row < n) {
            float inv = cnt ? 1.0f / fmaxf(cnt[row], 1.0f) : 1.0f;
            float4 mv = reinterpret_cast<const float4*>(agg + (size_t)row * FDIM)[c4];
            float4 xv = reinterpret_cast<const float4*>(xin + (size_t)row * FDIM)[c4];
            float* mp = &m_s[r][c4 * 4];
            mp[0] = mv.x * inv; mp[1] = mv.y * inv; mp[2] = mv.z * inv; mp[3] = mv.w * inv;
            float* xp = &x_s[r][c4 * 4];
            xp[0] = xv.x; xp[1] = xv.y; xp[2] = xv.z; xp[3] = xv.w;
        }
    }
    __syncthreads();
    int j = tid & 127;
    int rh = tid >> 7;
    float acc[8];
    float bj = bias[j];
#pragma unroll
    for (int r = 0; r < 8; ++r) acc[r] = bj;
#pragma unroll 4
    for (int k = 0; k < FDIM; ++k) {
        float wl = Wl[k * FDIM + j];
        float wr = Wr[k * FDIM + j];
#pragma unroll
        for (int r = 0; r < 8; ++r)
            acc[r] += m_s[rh * 8 + r][k] * wl + x_s[rh * 8 + r][k] * wr;
    }
#pragma unroll
    for (int r = 0; r < 8; ++r) {
        int row = row0 + rh * 8 + r;
        if (row < n) {
            float v = acc[r];
            if (RELU) v = fmaxf(v, 0.0f);
            out[(size_t)row * FDIM + j] = v;
        }
    }
}

extern "C" void kernel_launch(void* const* d_in, const int* in_sizes, int n_in,
                              void* d_out, int out_size, void* d_ws, size_t ws_size,
                              hipStream_t stream) {
    const float* x   = (const float*)d_in[0];
    const int*   ei  = (const int*)d_in[1];
    const float* Wl0 = (const float*)d_in[2];
    const float* Wr0 = (const float*)d_in[3];
    const float* b0  = (const float*)d_in[4];
    const float* Wl1 = (const float*)d_in[5];
    const float* Wr1 = (const float*)d_in[6];
    const float* b1  = (const float*)d_in[7];

    int N = in_sizes[0] / FDIM;   // 50000
    int E = in_sizes[1] / 2;      // 800000
    const int* src = ei;
    const int* dst = ei + E;

    size_t featBytes  = (size_t)N * FDIM * sizeof(float);   // 25.6 MB
    size_t featBytesB = (size_t)N * FDIM * sizeof(short);   // 12.8 MB
    int edgeBlocks = (E + 255) / 256;                       // 3125
    int M = NGRP * N;                                       // 400000
    int blocksA = (M + 1023) / 1024;                        // 391 (must be <= 512 for scanA3 v2)

    // ---- workspace layout (29.1 MB; CSR temps overlay the dead mb region) ----
    const size_t o_bsum = 0x0;                    // 4 KB
    const size_t o_rp   = 0x1000;                 // N+1 ints
    const size_t o_wt0  = 0x33000;                // 64 KB
    const size_t o_wt1  = 0x43000;                // 64 KB
    const size_t o_eid  = 0x53000;                // E ints (3.2 MB)
    const size_t o_xb   = 0x361000;               // N*128 bf16 (x, then h in-place)
    const size_t o_mb   = o_xb + featBytesB;      // N*128 bf16 (mean), overlays CSR temps
    const size_t need   = o_mb + featBytesB;      // ~29.14 MB
    const size_t s_degg = o_mb + 0x0;             // 8N ints
    const size_t s_off  = o_mb + 0x187000;        // 8N+1 ints
    const size_t s_cur  = o_mb + 0x30E000;        // 8N ints
    const size_t s_eidt = o_mb + 0x495000;        // E ints

    if (ws_size >= need && blocksA <= 512) {
        int*   bsum   = (int*)((char*)d_ws + o_bsum);
        int*   rp     = (int*)((char*)d_ws + o_rp);
        short* Wt0    = (short*)((char*)d_ws + o_wt0);
        short* Wt1    = (short*)((char*)d_ws + o_wt1);
        int*   eid    = (int*)((char*)d_ws + o_eid);
        short* xb     = (short*)((char*)d_ws + o_xb);
        short* mb     = (short*)((char*)d_ws + o_mb);
        int*   degg   = (int*)((char*)d_ws + s_degg);
        int*   off    = (int*)((char*)d_ws + s_off);
        int*   cursor = (int*)((char*)d_ws + s_cur);
        int*   eidt   = (int*)((char*)d_ws + s_eidt);
        float* outF   = (float*)d_out;

        // prologue: zero(degg) + x->bf16 + weight transpose, one kernel
        int nz  = M / 4;                          // 100000 int4
        int n4x = N * FDIM / 4;                   // 1.6M float4
        int ZB = (nz + 255) / 256;                // 391
        int XB = (n4x + 255) / 256;               // 6250
        int WB = (65536 + 255) / 256;             // 256
        prologue_kernel<<<ZB + XB + WB, 256, 0, stream>>>(
            (int4*)degg, nz, x, xb, n4x, Wl0, Wr0, Wl1, Wr1, Wt0, Wt1, ZB, XB);

        // XCD-sharded CSR build
        hist8_kernel<<<edgeBlocks, 256, 0, stream>>>(dst, degg, E, N);
        scanA1_kernel<<<blocksA, 256, 0, stream>>>(degg, off, bsum, M);
        scanA3_kernel<<<blocksA, 256, 0, stream>>>(off, cursor, bsum, blocksA, M, E);
        rp_kernel<<<(N + 256) / 256, 256, 0, stream>>>(off, rp, N, E);
        fill8_kernel<<<edgeBlocks, 256, 0, stream>>>(src, dst, cursor, eidt, E, N);
        merge_kernel<<<(N + 255) / 256, 256, 0, stream>>>(off, eidt, rp, eid, N);

        int gatherBlocks = (N + 3) / 4;
        int gemmBlocks   = (N + 63) / 64;
        // layer 0: h(bf16, in-place over xb) = relu([mean|x] @ Wcat0 + b0)
        gather_kernel<<<gatherBlocks, 256, 0, stream>>>(xb, rp, eid, mb, N);
        gemm_mfma_kernel<true, false><<<gemmBlocks, 256, 0, stream>>>(mb, xb, Wt0, b0, nullptr, xb, N);
        // layer 1: out(f32) = [mean(h)|h] @ Wcat1 + b1
        gather_kernel<<<gatherBlocks, 256, 0, stream>>>(xb, rp, eid, mb, N);
        gemm_mfma_kernel<false, true><<<gemmBlocks, 256, 0, stream>>>(mb, xb, Wt1, b1, outF, nullptr, N);
    } else {
        // fallback: proven atomic path
        float* cnt = (float*)d_ws;
        float* h   = (float*)((char*)d_ws + (1 << 18));
        float* msg = (float*)d_out;
        int gemmBlocks = (N + 15) / 16;

        hipMemsetAsync(cnt, 0, (size_t)N * sizeof(float), stream);
        degree_kernel<<<edgeBlocks, 256, 0, stream>>>(dst, cnt, E);

        hipMemsetAsync(msg, 0, featBytes, stream);
        scatter_kernel<<<(E * 64 + 255) / 256, 256, 0, stream>>>(x, src, dst, msg, E);
        gemm_kernel<true><<<gemmBlocks, 256, 0, stream>>>(msg, cnt, x, Wl0, Wr0, b0, h, N);

        hipMemsetAsync(msg, 0, featBytes, stream);
        scatter_kernel<<<(E * 64 + 255) / 256, 256, 0, stream>>>(h, src, dst, msg, E);
        gemm_kernel<false><<<gemmBlocks, 256, 0, stream>>>(msg, cnt, h, Wl1, Wr1, b1, msg, N);
    }
}